// Round 4
// baseline (308.250 us; speedup 1.0000x reference)
//
#include <hip/hip_runtime.h>
#include <hip/hip_bf16.h>

// MagnusLadder: out[k] = expm(A*dt)^k @ x0, k=0..8191, A = -0.1*I + skew-tridiag(+-0.5)
// Closed form via DST diagonalization:
//   A = -0.1 I + D (i T_r) D^-1,  D = diag(i^j),  T_r = V diag(lam) V,
//   V[j][m] = sqrt(2/257) sin((j+1)(m+1)pi/257),  lam_m = cos((m+1)pi/257)
//   out[k] = e^{-0.1 k dt} Re{ D V E_k V D^-1 x0 },  E_k = diag(e^{i k dt lam})
// Even output rows need only V@ur(k), odd rows only V@ui(k)  (signs folded into Ve/Vo).
//
// k2 v3: raw s_barrier with lgkmcnt-only drain (stores NEVER drained in-loop, T4),
// phase A(r+1) software-pipelined before phase B(r), nontemporal output stores.

#define DIMN 256
#define BB   32
#define TSTEPS 8192
#define KT   32            // k-steps per workgroup in k2
#define DTF  0.01f

typedef __attribute__((ext_vector_type(8))) short bf16x8;
typedef __attribute__((ext_vector_type(4))) float f32x4;

static __device__ __forceinline__ short f2bf(float f) {
    union { __hip_bfloat16 h; short s; } u;
    u.h = __float2bfloat16(f);
    return u.s;
}

// ---------------- K1: build Vfold (bf16) and yr/yi (fp32) in workspace ----------------
__global__ __launch_bounds__(256) void k1_prep(const float* __restrict__ x0,
                                               unsigned short* __restrict__ vfold,
                                               float* __restrict__ yr,
                                               float* __restrict__ yi) {
    const float PI257 = (float)(3.14159265358979323846 / 257.0);
    const float S257  = sqrtf(2.0f / 257.0f);
    const int g = blockIdx.x;
    const int t = threadIdx.x;

    __shared__ float x0s[256 * 32];
    __shared__ float ve[256], vo[256];
    __shared__ float psr[8][32], psi[8][32];

    if (g < 256) {
        // one V row (output row j = g), sign-folded, to bf16
        const int j = g, J = j >> 1, p = j & 1, m = t;
        const int n = ((j + 1) * (m + 1)) % 514;          // exact period reduction
        const float v = S257 * sinf((float)n * PI257);
        float sgn;
        if (p == 0) sgn = (J & 1) ? -1.f : 1.f;
        else        sgn = (J & 1) ?  1.f : -1.f;
        vfold[p * 32768 + J * 256 + m] = (unsigned short)f2bf(sgn * v);
    } else {
        // one y row (spectral index m = g-256)
        const int m = g - 256;
        for (int idx = t; idx < 256 * 32; idx += 256) x0s[idx] = x0[idx];
        const int n = ((m + 1) * (t + 1)) % 514;
        const float v = S257 * sinf((float)n * PI257);
        const int j = t;
        float veJ = 0.f, voJ = 0.f;
        if ((j & 1) == 0) veJ = ((j & 3) == 0) ? v : -v;
        else              voJ = ((j & 3) == 3) ? v : -v;
        ve[j] = veJ; vo[j] = voJ;
        __syncthreads();
        const int b = t & 31, jg = t >> 5;
        float sr = 0.f, si = 0.f;
#pragma unroll
        for (int jj2 = 0; jj2 < 32; ++jj2) {
            const int jj = jg * 32 + jj2;
            sr += ve[jj] * x0s[jj * 32 + b];
            si += vo[jj] * x0s[jj * 32 + b];
        }
        psr[jg][b] = sr; psi[jg][b] = si;
        __syncthreads();
        if (t < 32) {
            float asr = 0.f, asi = 0.f;
#pragma unroll
            for (int q = 0; q < 8; ++q) { asr += psr[q][t]; asi += psi[q][t]; }
            yr[m * 32 + t] = asr;
            yi[m * 32 + t] = asi;
        }
    }
}

// ---------------- K2: main — 256 WGs x 512 threads, KT k's per WG ----------------
// LDS u layout per [dbuf][kw][plane]: element offset for (b, m), m = ks*32 + g*8 + i:
//   off = b*256 + ((ks ^ (b&7))<<3) + (g<<6) + i   -> all ds accesses <=2-way (free)
__global__ __launch_bounds__(512, 2) void k2_main(const unsigned short* __restrict__ vfold,
                                                  const float* __restrict__ yr,
                                                  const float* __restrict__ yi,
                                                  float* __restrict__ out) {
    __shared__ unsigned short ubuf[2][2][2][8192];   // 128 KiB: [dbuf][kw][ur/ui][b,m swz]
    const float PI257   = (float)(3.14159265358979323846 / 257.0);
    const float INV2PI  = (float)(1.0 / (2.0 * 3.14159265358979323846));
    const int tid  = threadIdx.x;
    const int lane = tid & 63;
    const int wave = tid >> 6;
    const int k0   = blockIdx.x * KT;

    // ---- Phase-A role: thread owns modes m0..m0+7 at batch cols bA and bA+16 ----
    const int bA   = tid & 15;
    const int mblk = tid >> 4;            // 0..31
    const int m0   = mblk << 3;

    float threv[8], yrv0[8], yiv0[8], yrv1[8], yiv1[8];
#pragma unroll
    for (int i = 0; i < 8; ++i) {
        const int m = m0 + i;
        const float lam = cosf((float)(m + 1) * PI257);
        threv[i] = DTF * lam * INV2PI;               // per-step phase in revolutions
        yrv0[i] = yr[m * 32 + bA];       yiv0[i] = yi[m * 32 + bA];
        yrv1[i] = yr[m * 32 + bA + 16];  yiv1[i] = yi[m * 32 + bA + 16];
    }
    // LDS write offsets (ushort elements) for (b, m0..m0+7)
    const int ksA = m0 >> 5, gA2 = (m0 >> 3) & 3;
    const int wOff0 = bA * 256        + (((ksA ^ (bA & 7)))        << 3) + (gA2 << 6);
    const int wOff1 = (bA + 16) * 256 + (((ksA ^ ((bA + 16) & 7))) << 3) + (gA2 << 6);

    // ---- Phase-B role: wave owns 64 rows (4 tiles) x 16 cols of one parity ----
    const int p  = wave & 1;
    const int nt = (wave >> 1) & 1;
    const int rh = wave >> 2;             // 0/1: row half
    const int rA = lane & 15;
    const int gA = lane >> 4;
    bf16x8 afr[4][8];                     // A fragments resident for whole kernel
#pragma unroll
    for (int rt = 0; rt < 4; ++rt) {
        const unsigned short* arow =
            vfold + p * 32768 + (rh * 64 + rt * 16 + rA) * 256 + gA * 8;
#pragma unroll
        for (int ks = 0; ks < 8; ++ks)
            afr[rt][ks] = *reinterpret_cast<const bf16x8*>(arow + ks * 32);
    }
    const int brd   = nt * 16 + rA;
    const int h     = brd & 7;
    const int rbase = brd * 256 + (gA << 6);

    float dec = expf(-0.001f * (float)k0);           // -0.1*dt = -0.001
    const float decr = expf(-0.001f);

    // Phase A: compute ur/ui for round rr (k = k0+2rr, k0+2rr+1) into dbuf rr&1
    auto phaseA = [&](int rr) {
        const int d = rr & 1;
#pragma unroll
        for (int kw = 0; kw < 2; ++kw) {
            const float kf = (float)(k0 + 2 * rr + kw);
            bf16x8 vur0, vui0, vur1, vui1;
#pragma unroll
            for (int i = 0; i < 8; ++i) {
                const float ang = kf * threv[i];               // revolutions
                const float fr  = ang - floorf(ang);           // exact reduction
                const float c   = __builtin_amdgcn_cosf(fr);
                const float s   = __builtin_amdgcn_sinf(fr);
                vur0[i] = f2bf(c * yrv0[i] - s * yiv0[i]);
                vui0[i] = f2bf(c * yiv0[i] + s * yrv0[i]);
                vur1[i] = f2bf(c * yrv1[i] - s * yiv1[i]);
                vui1[i] = f2bf(c * yiv1[i] + s * yrv1[i]);
            }
            *reinterpret_cast<bf16x8*>(&ubuf[d][kw][0][wOff0]) = vur0;
            *reinterpret_cast<bf16x8*>(&ubuf[d][kw][1][wOff0]) = vui0;
            *reinterpret_cast<bf16x8*>(&ubuf[d][kw][0][wOff1]) = vur1;
            *reinterpret_cast<bf16x8*>(&ubuf[d][kw][1][wOff1]) = vui1;
        }
    };

    // Barrier with LDS-only drain: global stores stay in flight (never vmcnt(0)).
    auto barrier_lgkm = [&]() {
        __builtin_amdgcn_sched_barrier(0);
        asm volatile("s_waitcnt lgkmcnt(0)" ::: "memory");
        __builtin_amdgcn_s_barrier();
        asm volatile("" ::: "memory");
        __builtin_amdgcn_sched_barrier(0);
    };

    phaseA(0);
    barrier_lgkm();

    const int ROUNDS = KT / 2;
    for (int r = 0; r < ROUNDS; ++r) {
        const int d = r & 1;
        if (r + 1 < ROUNDS) phaseA(r + 1);   // overlaps with phase B below (same interval)

        // ---------- Phase B: MFMA + store, both k's of round r ----------
#pragma unroll
        for (int kw = 0; kw < 2; ++kw) {
            const unsigned short* up = &ubuf[d][kw][p][0];
            float* outk = out + (size_t)(k0 + 2 * r + kw) * 8192;
            f32x4 acc[4];
#pragma unroll
            for (int rt = 0; rt < 4; ++rt) acc[rt] = (f32x4){0.f, 0.f, 0.f, 0.f};
#pragma unroll
            for (int ks = 0; ks < 8; ++ks) {
                const bf16x8 bfr =
                    *reinterpret_cast<const bf16x8*>(up + rbase + ((ks ^ h) << 3));
#pragma unroll
                for (int rt = 0; rt < 4; ++rt)
                    acc[rt] = __builtin_amdgcn_mfma_f32_16x16x32_bf16(
                        afr[rt][ks], bfr, acc[rt], 0, 0, 0);
            }
#pragma unroll
            for (int rt = 0; rt < 4; ++rt) {
#pragma unroll
                for (int q = 0; q < 4; ++q) {
                    const int j = 2 * (rh * 64 + rt * 16 + gA * 4 + q) + p;
                    __builtin_nontemporal_store(acc[rt][q] * dec, &outk[j * 32 + brd]);
                }
            }
            dec *= decr;
        }

        if (r + 1 < ROUNDS) barrier_lgkm();
    }
}

extern "C" void kernel_launch(void* const* d_in, const int* in_sizes, int n_in,
                              void* d_out, int out_size, void* d_ws, size_t ws_size,
                              hipStream_t stream) {
    const float* x0 = (const float*)d_in[1];          // [256][32] fp32
    float* out = (float*)d_out;                       // [8192][256][32] fp32

    unsigned short* vfold = (unsigned short*)d_ws;                    // 128 KiB
    float* yr = (float*)((char*)d_ws + 131072);                       // 32 KiB
    float* yi = (float*)((char*)d_ws + 131072 + 32768);               // 32 KiB

    k1_prep<<<512, 256, 0, stream>>>(x0, vfold, yr, yi);
    k2_main<<<256, 512, 0, stream>>>(vfold, yr, yi, out);
}

// Round 5
// 274.389 us; speedup vs baseline: 1.1234x; 1.1234x over previous
//
#include <hip/hip_runtime.h>
#include <hip/hip_bf16.h>

// MagnusLadder: out[k] = expm(A*dt)^k @ x0, k=0..8191, A = -0.1*I + skew-tridiag(+-0.5)
// Closed form via DST diagonalization:
//   A = -0.1 I + D (i T_r) D^-1,  D = diag(i^j),  T_r = V diag(lam) V,
//   V[j][m] = sqrt(2/257) sin((j+1)(m+1)pi/257),  lam_m = cos((m+1)pi/257)
//   out[k] = e^{-0.1 k dt} Re{ D V E_k V D^-1 x0 },  E_k = diag(e^{i k dt lam})
// Even output rows need only V@ur(k), odd rows only V@ui(k)  (signs folded into Ve/Vo).
//
// k2 v4: OPERAND-SWAPPED MFMA (D = u^T * V, V symmetric) so each lane's 4 acc regs
// are 4 consecutive b's -> global_store_dwordx4 (1 KiB/wave-instr, full 64B lines).
// Plain __syncthreads (v2-proven), no nontemporal, no sched_barrier (v3 post-mortem).

#define DIMN 256
#define BB   32
#define TSTEPS 8192
#define KT   32            // k-steps per workgroup in k2
#define DTF  0.01f

typedef __attribute__((ext_vector_type(8))) short bf16x8;
typedef __attribute__((ext_vector_type(4))) float f32x4;

static __device__ __forceinline__ short f2bf(float f) {
    union { __hip_bfloat16 h; short s; } u;
    u.h = __float2bfloat16(f);
    return u.s;
}

// ---------------- K1: build Vfold (bf16) and yr/yi (fp32) in workspace ----------------
// vfold layout: [parity][J][m] ushort, parity 0: Ve[J][m] = (-1)^J     * V[2J  ][m]
//                                      parity 1: Vo[J][m] = (-1)^(J+1) * V[2J+1][m]
__global__ __launch_bounds__(256) void k1_prep(const float* __restrict__ x0,
                                               unsigned short* __restrict__ vfold,
                                               float* __restrict__ yr,
                                               float* __restrict__ yi) {
    const float PI257 = (float)(3.14159265358979323846 / 257.0);
    const float S257  = sqrtf(2.0f / 257.0f);
    const int g = blockIdx.x;
    const int t = threadIdx.x;

    __shared__ float x0s[256 * 32];
    __shared__ float ve[256], vo[256];
    __shared__ float psr[8][32], psi[8][32];

    if (g < 256) {
        // one V row (output row j = g), sign-folded, to bf16
        const int j = g, J = j >> 1, p = j & 1, m = t;
        const int n = ((j + 1) * (m + 1)) % 514;          // exact period reduction
        const float v = S257 * sinf((float)n * PI257);
        float sgn;
        if (p == 0) sgn = (J & 1) ? -1.f : 1.f;
        else        sgn = (J & 1) ?  1.f : -1.f;
        vfold[p * 32768 + J * 256 + m] = (unsigned short)f2bf(sgn * v);
    } else {
        // one y row (spectral index m = g-256)
        const int m = g - 256;
        for (int idx = t; idx < 256 * 32; idx += 256) x0s[idx] = x0[idx];
        const int n = ((m + 1) * (t + 1)) % 514;
        const float v = S257 * sinf((float)n * PI257);
        const int j = t;
        float veJ = 0.f, voJ = 0.f;
        if ((j & 1) == 0) veJ = ((j & 3) == 0) ? v : -v;
        else              voJ = ((j & 3) == 3) ? v : -v;
        ve[j] = veJ; vo[j] = voJ;
        __syncthreads();
        const int b = t & 31, jg = t >> 5;
        float sr = 0.f, si = 0.f;
#pragma unroll
        for (int jj2 = 0; jj2 < 32; ++jj2) {
            const int jj = jg * 32 + jj2;
            sr += ve[jj] * x0s[jj * 32 + b];
            si += vo[jj] * x0s[jj * 32 + b];
        }
        psr[jg][b] = sr; psi[jg][b] = si;
        __syncthreads();
        if (t < 32) {
            float asr = 0.f, asi = 0.f;
#pragma unroll
            for (int q = 0; q < 8; ++q) { asr += psr[q][t]; asi += psi[q][t]; }
            yr[m * 32 + t] = asr;
            yi[m * 32 + t] = asi;
        }
    }
}

// ---------------- K2: main — 256 WGs x 512 threads, KT k's per WG ----------------
// LDS u layout per [dbuf][kw][plane]: 32x32 grid of 16B cells (b, mo), mo = m/8:
//   cellIdx(b, mo) = b*32 + (mo & 24) + ((mo ^ (b & 7)) & 7)    (shorts off = cell*8)
// Both the phase-A writes (16 b x 4 consecutive mo per wave) and the phase-B reads
// (16 b x 4 consecutive mo per wave) hit every bank exactly 8x per instr = BW-minimum.
__global__ __launch_bounds__(512, 2) void k2_main(const unsigned short* __restrict__ vfold,
                                                  const float* __restrict__ yr,
                                                  const float* __restrict__ yi,
                                                  float* __restrict__ out) {
    __shared__ unsigned short ubuf[2][2][2][8192];   // 128 KiB: [dbuf][kw][ur/ui][cells]
    const float PI257   = (float)(3.14159265358979323846 / 257.0);
    const float INV2PI  = (float)(1.0 / (2.0 * 3.14159265358979323846));
    const int tid  = threadIdx.x;
    const int lane = tid & 63;
    const int wave = tid >> 6;
    const int k0   = blockIdx.x * KT;

    // ---- Phase-A role: thread owns modes m0..m0+7 (octet mblk) at cols bA, bA+16 ----
    const int bA   = tid & 15;
    const int mblk = tid >> 4;            // 0..31 = mo
    const int m0   = mblk << 3;

    float threv[8], yrv0[8], yiv0[8], yrv1[8], yiv1[8];
#pragma unroll
    for (int i = 0; i < 8; ++i) {
        const int m = m0 + i;
        const float lam = cosf((float)(m + 1) * PI257);
        threv[i] = DTF * lam * INV2PI;               // per-step phase in revolutions
        yrv0[i] = yr[m * 32 + bA];       yiv0[i] = yi[m * 32 + bA];
        yrv1[i] = yr[m * 32 + bA + 16];  yiv1[i] = yi[m * 32 + bA + 16];
    }
    // LDS write offsets (ushort elements) for cells (bA, mblk) and (bA+16, mblk)
    const int C0    = (mblk & 24) + ((mblk ^ (bA & 7)) & 7);
    const int wOff0 = bA * 256 + C0 * 8;
    const int wOff1 = wOff0 + 16 * 256;

    // ---- Phase-B role: wave owns 32 parity-rows J (x all 32 b) of parity p ----
    const int p  = wave & 1;              // 0: even j (ur), 1: odd j (ui)
    const int wp = wave >> 1;             // 0..3: J-block
    const int rA = lane & 15;
    const int gA = lane >> 4;
    const int rl7 = rA & 7;

    // B-operand: V rows (sign-folded), resident in VGPRs: [ntile][ks]
    bf16x8 bfrv[2][8];
#pragma unroll
    for (int ntile = 0; ntile < 2; ++ntile) {
        const unsigned short* vrow =
            vfold + p * 32768 + (wp * 32 + ntile * 16 + rA) * 256 + gA * 8;
#pragma unroll
        for (int ks = 0; ks < 8; ++ks)
            bfrv[ntile][ks] = *reinterpret_cast<const bf16x8*>(vrow + ks * 32);
    }

    float dec = expf(-0.001f * (float)k0);           // -0.1*dt = -0.001
    const float decr = expf(-0.001f);

    for (int r = 0; r < KT / 2; ++r) {
        const int d = r & 1;
        // ---------- Phase A: ur/ui for k and k+1 into LDS ----------
#pragma unroll
        for (int kw = 0; kw < 2; ++kw) {
            const float kf = (float)(k0 + 2 * r + kw);
            bf16x8 vur0, vui0, vur1, vui1;
#pragma unroll
            for (int i = 0; i < 8; ++i) {
                const float ang = kf * threv[i];               // revolutions
                const float fr  = ang - floorf(ang);           // exact reduction
                const float c   = __builtin_amdgcn_cosf(fr);
                const float s   = __builtin_amdgcn_sinf(fr);
                vur0[i] = f2bf(c * yrv0[i] - s * yiv0[i]);
                vui0[i] = f2bf(c * yiv0[i] + s * yrv0[i]);
                vur1[i] = f2bf(c * yrv1[i] - s * yiv1[i]);
                vui1[i] = f2bf(c * yiv1[i] + s * yrv1[i]);
            }
            *reinterpret_cast<bf16x8*>(&ubuf[d][kw][0][wOff0]) = vur0;
            *reinterpret_cast<bf16x8*>(&ubuf[d][kw][1][wOff0]) = vui0;
            *reinterpret_cast<bf16x8*>(&ubuf[d][kw][0][wOff1]) = vur1;
            *reinterpret_cast<bf16x8*>(&ubuf[d][kw][1][wOff1]) = vui1;
        }
        __syncthreads();   // single barrier per round; double buffer covers WAR

        // ---------- Phase B: operand-swapped MFMA + dwordx4 store, both k's ----------
#pragma unroll
        for (int kw = 0; kw < 2; ++kw) {
            const unsigned short* up = &ubuf[d][kw][p][0];
            float* outk = out + (size_t)(k0 + 2 * r + kw) * 8192;
            f32x4 acc[2][2];
#pragma unroll
            for (int mt = 0; mt < 2; ++mt)
#pragma unroll
                for (int ntile = 0; ntile < 2; ++ntile)
                    acc[mt][ntile] = (f32x4){0.f, 0.f, 0.f, 0.f};
#pragma unroll
            for (int ks = 0; ks < 8; ++ks) {
                const int mo = ks * 4 + gA;
                const int csw = (mo & 24) + ((mo ^ rl7) & 7);
#pragma unroll
                for (int mt = 0; mt < 2; ++mt) {
                    // A-operand: u^T fragment — lane holds u[m-octet][b = mt*16+rA]
                    const bf16x8 afr = *reinterpret_cast<const bf16x8*>(
                        up + (mt * 16 + rA) * 256 + csw * 8);
#pragma unroll
                    for (int ntile = 0; ntile < 2; ++ntile)
                        acc[mt][ntile] = __builtin_amdgcn_mfma_f32_16x16x32_bf16(
                            afr, bfrv[ntile][ks], acc[mt][ntile], 0, 0, 0);
                }
            }
            // D: row(M) = b = mt*16 + gA*4 + q (4 consecutive floats!), col(N) = J
#pragma unroll
            for (int ntile = 0; ntile < 2; ++ntile) {
                const int j = 2 * (wp * 32 + ntile * 16 + rA) + p;
#pragma unroll
                for (int mt = 0; mt < 2; ++mt) {
                    f32x4 v4;
#pragma unroll
                    for (int q = 0; q < 4; ++q) v4[q] = acc[mt][ntile][q] * dec;
                    *reinterpret_cast<f32x4*>(&outk[j * 32 + mt * 16 + gA * 4]) = v4;
                }
            }
            dec *= decr;
        }
    }
}

extern "C" void kernel_launch(void* const* d_in, const int* in_sizes, int n_in,
                              void* d_out, int out_size, void* d_ws, size_t ws_size,
                              hipStream_t stream) {
    const float* x0 = (const float*)d_in[1];          // [256][32] fp32
    float* out = (float*)d_out;                       // [8192][256][32] fp32

    unsigned short* vfold = (unsigned short*)d_ws;                    // 128 KiB
    float* yr = (float*)((char*)d_ws + 131072);                       // 32 KiB
    float* yi = (float*)((char*)d_ws + 131072 + 32768);               // 32 KiB

    k1_prep<<<512, 256, 0, stream>>>(x0, vfold, yr, yi);
    k2_main<<<256, 512, 0, stream>>>(vfold, yr, yi, out);
}